// Round 15
// baseline (160.420 us; speedup 1.0000x reference)
//
#include <hip/hip_runtime.h>
#include <hip/hip_bf16.h>

#define NN 6144
#define HEADS 4
#define DIN 256
#define DOUT 64

typedef __bf16 bf16_t;
typedef bf16_t bf16x8 __attribute__((ext_vector_type(8)));
typedef float f32x16 __attribute__((ext_vector_type(16)));
typedef float f32x4 __attribute__((ext_vector_type(4)));
typedef unsigned u32x4 __attribute__((ext_vector_type(4)));

#if __has_builtin(__builtin_amdgcn_exp2f)
#define EXP2(x) __builtin_amdgcn_exp2f(x)
#else
#define EXP2(x) exp2f(x)
#endif

static __device__ __forceinline__ f32x16 zero16() {
  f32x16 z;
#pragma unroll
  for (int i = 0; i < 16; ++i) z[i] = 0.0f;
  return z;
}

static __device__ __forceinline__ bf16x8 ldg8(const bf16_t* p) {
  return *reinterpret_cast<const bf16x8*>(p);
}

// pack two f32 -> one u32 of 2 bf16 (element 0 in low half)
static __device__ __forceinline__ unsigned pk2(float a, float b) {
  union { bf16_t h[2]; unsigned u; } z;
  z.h[0] = (bf16_t)a;
  z.h[1] = (bf16_t)b;
  return z.u;
}

// v_permlane32_swap_b32: x.hi32lanes <-> y.lo32lanes
static __device__ __forceinline__ void pswap(unsigned& x, unsigned& y) {
  asm("v_permlane32_swap_b32 %0, %1" : "+v"(x), "+v"(y));
}

// non-temporal 16B read (read-once adj stream; don't evict K/V from L2)
static __device__ __forceinline__ f32x4 ldnt4(const float* p) {
  return __builtin_nontemporal_load(reinterpret_cast<const f32x4*>(p));
}

#define SCHED0() __builtin_amdgcn_sched_barrier(0)
#define VW(N)                                                   \
  asm volatile("s_waitcnt vmcnt(" #N ")" ::: "memory");         \
  SCHED0();

// ---------------- prepW: W -> transposed bf16 (scale folded into WQ) ONLY.
// (out/denom zeroing moved to hipMemsetAsync graph nodes; h conversion moved
// into proj's LDS.)
__global__ __launch_bounds__(256) void prepw_kernel(
    const float* __restrict__ WQ, const float* __restrict__ WK,
    const float* __restrict__ WV, bf16_t* __restrict__ Wt) {
  int stride = gridDim.x * blockDim.x;
  int idx = blockIdx.x * blockDim.x + threadIdx.x;
  const float c2 = 0.0625f * 1.4426950408889634f;  // (1/sqrt(256)) * log2(e)
  for (int i = idx; i < 3 * HEADS * DOUT * DIN; i += stride) {
    int d = i & (DIN - 1);
    int o = (i >> 8) & (DOUT - 1);
    int hh = (i >> 14) & (HEADS - 1);
    int m = i >> 16;
    const float* W = (m == 0) ? WQ : (m == 1) ? WK : WV;
    float v = W[(hh * DIN + d) * DOUT + o];
    if (m == 0) v *= c2;
    Wt[i] = (bf16_t)v;  // Wt[m][hh][o][d]
  }
}

// ---------------- proj: converts its own 64 h-rows f32->bf16 into LDS
// (pad 264 bf16/row: stride 528 B = 132 dwords == 4 mod 32 -> conflict-free
// b128 column reads), then Qb row-major [H][N][64]; Kf/Vf fragment order.
__global__ __launch_bounds__(256) void proj_kernel(
    const float* __restrict__ h, const bf16_t* __restrict__ Wt,
    const float* __restrict__ bQ, const float* __restrict__ bK,
    const float* __restrict__ bV,
    bf16_t* __restrict__ Qb, bf16_t* __restrict__ Kf, bf16_t* __restrict__ Vf) {
  __shared__ __align__(16) bf16_t hbl[64][264];
  const float c2 = 0.0625f * 1.4426950408889634f;
  int tid = threadIdx.x;
  int w = tid >> 6, l = tid & 63;
  int l31 = l & 31, lh = l >> 5;
  int hh = blockIdx.y;
  int n0 = blockIdx.x * 64;

  // convert h rows n0..n0+63 into LDS (16 f32x4 per thread)
#pragma unroll
  for (int i = tid; i < 4096; i += 256) {
    int r = i >> 6, c4 = i & 63;
    f32x4 v = *reinterpret_cast<const f32x4*>(h + (size_t)(n0 + r) * DIN + 4 * c4);
    bf16_t* dst = &hbl[r][4 * c4];
    dst[0] = (bf16_t)v[0];
    dst[1] = (bf16_t)v[1];
    dst[2] = (bf16_t)v[2];
    dst[3] = (bf16_t)v[3];
  }
  __syncthreads();

#pragma unroll
  for (int s = 0; s < 3; ++s) {
    int t = w * 3 + s;  // 12 tiles: 0-3 Q, 4-7 K, 8-11 V
    if (t < 8) {
      int m = t >> 2;            // 0=Q, 1=K
      int rh = (t >> 1) & 1;     // row half (key half)
      int oh = t & 1;            // out-col half
      const bf16_t* arow = &hbl[rh * 32 + l31][8 * lh];
      const bf16_t* brow = Wt + ((m * HEADS + hh) * DOUT + oh * 32 + l31) * DIN + 8 * lh;
      f32x16 acc = zero16();
#pragma unroll
      for (int kc = 0; kc < 16; ++kc)
        acc = __builtin_amdgcn_mfma_f32_32x32x16_bf16(ldg8(arow + kc * 16),
                                                      ldg8(brow + kc * 16), acc, 0, 0, 0);
      const float* bias = (m == 0) ? bQ : bK;
      float bv = bias[hh * DOUT + oh * 32 + l31];
      if (m == 0) {
        bv *= c2;
        bf16_t* outp = Qb + (size_t)(hh * NN + n0 + rh * 32) * DOUT + oh * 32 + l31;
#pragma unroll
        for (int r = 0; r < 16; ++r) {
          int q = (r & 3) + 8 * (r >> 2) + 4 * lh;
          outp[q * DOUT] = (bf16_t)(acc[r] + bv);
        }
      } else {
        int o = oh * 32 + l31;
        bf16_t* outp = Kf + (size_t)hh * 393216 + (n0 >> 6) * 4096 + rh * 2048 +
                       (o >> 4) * 512 + ((o >> 3) & 1) * 256 + (o & 7);
#pragma unroll
        for (int r = 0; r < 16; ++r) {
          int rr = (r & 3) + 8 * (r >> 2) + 4 * lh;  // key & 31
          outp[rr * 8] = (bf16_t)(acc[r] + bv);
        }
      }
    } else {
      int tt = t - 8;
      int oh = tt >> 1, nh = tt & 1;  // oh = d half, nh = key half
      const bf16_t* arow = Wt + ((2 * HEADS + hh) * DOUT + oh * 32 + l31) * DIN + 8 * lh;
      const bf16_t* brow = &hbl[nh * 32 + l31][8 * lh];
      f32x16 acc = zero16();
#pragma unroll
      for (int kc = 0; kc < 16; ++kc)
        acc = __builtin_amdgcn_mfma_f32_32x32x16_bf16(ldg8(arow + kc * 16),
                                                      ldg8(brow + kc * 16), acc, 0, 0, 0);
      int k6 = nh * 32 + l31;
      bf16_t* outp = Vf + (size_t)hh * 393216 + (n0 >> 6) * 4096 + oh * 2048 +
                     (k6 >> 4) * 512 + ((k6 >> 3) & 1) * 256 + (k6 & 7);
#pragma unroll
      for (int r = 0; r < 16; ++r) {
        int rr = (r & 3) + 8 * (r >> 2) + 4 * lh;  // d & 31
        float bvv = bV[hh * DOUT + oh * 32 + rr];
        outp[rr * 8] = (bf16_t)(acc[r] + bvv);
      }
    }
  }
}

// one iteration body (12-tile KSPLIT version). AIN = regs holding tile IT+1;
// AOUT = regs receiving tile IT+2. CUR = LDS buffer parity.
// vmcnt ledger: entry IN(8); +KV(16); +OUT(8). Compiler's vf wait = vmcnt(8)
// leaves OUT in flight; explicit VW(8) drains IN before its ds_write.
#define ATTN_BODY(AIN, AOUT, IT, CUR)                                          \
  {                                                                            \
    int tc = t0 + (IT);                                                        \
    if (tc >= 12) tc -= 12;                                                    \
    int tni = t0 + (IT) + 2;                                                   \
    if (tni >= 12) tni -= 12;                                                  \
    int chunk = ckb + tc * 4 + w;                                              \
    const bf16_t* kbase = Kh + (size_t)chunk * 4096 + l * 8;                   \
    const bf16_t* vbase = Vh + (size_t)chunk * 4096 + l * 8;                   \
    bf16x8 kf[8], vf[8];                                                       \
    _Pragma("unroll") for (int x = 0; x < 4; ++x) {                            \
      kf[x] = ldg8(kbase + x * 512);                                           \
      kf[4 + x] = ldg8(kbase + 2048 + x * 512);                                \
    }                                                                          \
    _Pragma("unroll") for (int x = 0; x < 4; ++x) {                            \
      vf[x] = ldg8(vbase + x * 512);                                           \
      vf[4 + x] = ldg8(vbase + 2048 + x * 512);                                \
    }                                                                          \
    SCHED0();                                                                  \
    if ((IT) < 10) { /* issue tile IT+2 */                                     \
      _Pragma("unroll") for (int i = 0; i < 8; ++i) {                          \
        int row = 8 * w + i;                                                   \
        AOUT[i] = ldnt4(adjq + (size_t)row * NN + tni * 256 + ((l ^ i) << 2)); \
      }                                                                        \
    }                                                                          \
    SCHED0();                                                                  \
    f32x4 av[8];                                                               \
    _Pragma("unroll") for (int t2 = 0; t2 < 2; ++t2)                           \
        _Pragma("unroll") for (int g = 0; g < 4; ++g) {                        \
      int c = 16 * w + 8 * t2 + 2 * g + lh;                                    \
      av[t2 * 4 + g] = *reinterpret_cast<const f32x4*>(                        \
          &smem[CUR][l31][(c ^ (l31 & 7)) << 2]);                              \
    }                                                                          \
    f32x16 s0 = zero16(), s1 = zero16();                                       \
    _Pragma("unroll") for (int kc = 0; kc < 4; ++kc) {                         \
      s0 = __builtin_amdgcn_mfma_f32_32x32x16_bf16(kf[kc], qf[kc], s0, 0, 0, 0);\
      s1 = __builtin_amdgcn_mfma_f32_32x32x16_bf16(kf[4 + kc], qf[kc], s1, 0, 0, 0);\
    }                                                                          \
    _Pragma("unroll") for (int t2 = 0; t2 < 2; ++t2) {                         \
      f32x16 st = t2 ? s1 : s0;                                                \
      float p[16];                                                             \
      _Pragma("unroll") for (int r = 0; r < 16; ++r) {                         \
        float pv = EXP2(st[r] * av[4 * t2 + (r >> 2)][r & 3]);                 \
        p[r] = pv;                                                             \
        sacc += pv;                                                            \
      }                                                                        \
      _Pragma("unroll") for (int c2 = 0; c2 < 2; ++c2) {                       \
        unsigned wA0 = pk2(p[8 * c2 + 0], p[8 * c2 + 1]);                      \
        unsigned wB0 = pk2(p[8 * c2 + 2], p[8 * c2 + 3]);                      \
        unsigned wA1 = pk2(p[8 * c2 + 4], p[8 * c2 + 5]);                      \
        unsigned wB1 = pk2(p[8 * c2 + 6], p[8 * c2 + 7]);                      \
        pswap(wA0, wA1);                                                       \
        pswap(wB0, wB1);                                                       \
        u32x4 pw;                                                              \
        pw[0] = wA0; pw[1] = wB0; pw[2] = wA1; pw[3] = wB1;                    \
        bf16x8 pb = __builtin_bit_cast(bf16x8, pw);                            \
        int kc = 2 * t2 + c2;                                                  \
        o0 = __builtin_amdgcn_mfma_f32_32x32x16_bf16(vf[kc], pb, o0, 0, 0, 0); \
        o1 = __builtin_amdgcn_mfma_f32_32x32x16_bf16(vf[4 + kc], pb, o1, 0, 0, 0);\
      }                                                                        \
    }                                                                          \
    if ((IT) < 11) { /* drain IN (tile IT+1), publish to buf[CUR^1] */         \
      VW(8)                                                                    \
      _Pragma("unroll") for (int i = 0; i < 8; ++i) {                          \
        int row = 8 * w + i;                                                   \
        *reinterpret_cast<f32x4*>(&smem[(CUR) ^ 1][row][l << 2]) = AIN[i];     \
      }                                                                        \
      asm volatile("s_waitcnt lgkmcnt(0)" ::: "memory");                       \
      SCHED0();                                                                \
      __builtin_amdgcn_s_barrier();                                           \
      SCHED0();                                                                \
    }                                                                          \
  }

// ---------------- attention: r14 structure (KSPLIT=2, depth-2 reg pipeline,
// XCD (head,half) affinity, column-phase rotation, NT stream).
__global__ __launch_bounds__(256, 2) void attn_kernel(
    const float* __restrict__ adj, const bf16_t* __restrict__ Qb,
    const bf16_t* __restrict__ Kf, const bf16_t* __restrict__ Vf,
    float* __restrict__ out, float* __restrict__ denom) {
  __shared__ __align__(16) float smem[2][32][256];  // 64 KB; reused for epilogue

  int tid = threadIdx.x;
  int w = tid >> 6, l = tid & 63;
  int l31 = l & 31, lh = l >> 5;

  int bid = blockIdx.x;
  int x = bid & 7;          // XCD
  int hh = x >> 1;          // head
  int ky = x & 1;           // key half
  int qt = bid >> 3;        // q-tile 0..191
  int q0 = qt * 32;
  int t0 = qt % 12;         // column-phase rotation within the half
  const int ckb = ky * 48;  // first 64-key chunk of this half

  // Q as B-fragment: col = q = l31, k = kc*16 + 8*lh + 0..7  (pre-scaled by c2)
  const bf16_t* Qrow = Qb + (size_t)(hh * NN + q0 + l31) * DOUT + 8 * lh;
  bf16x8 qf[4];
#pragma unroll
  for (int kc = 0; kc < 4; ++kc) qf[kc] = ldg8(Qrow + kc * 16);

  const bf16_t* Kh = Kf + (size_t)hh * 393216;
  const bf16_t* Vh = Vf + (size_t)hh * 393216;
  const float* adjq = adj + (size_t)hh * NN * NN + (size_t)q0 * NN + ky * 3072;

  f32x16 o0 = zero16(), o1 = zero16();
  float sacc = 0.0f;

  f32x4 aregA[8], aregB[8];

  // ---- prologue: issue tiles t0 -> A and t0+1 -> B; drain A only; write A
  // to LDS buf0 (swizzle on write: LDS[row][u] = G[row][u^(row&7)]).
#pragma unroll
  for (int i = 0; i < 8; ++i) {
    int row = 8 * w + i;
    aregA[i] = ldnt4(adjq + (size_t)row * NN + t0 * 256 + ((l ^ i) << 2));
  }
  int t1 = t0 + 1;
  if (t1 >= 12) t1 -= 12;
#pragma unroll
  for (int i = 0; i < 8; ++i) {
    int row = 8 * w + i;
    aregB[i] = ldnt4(adjq + (size_t)row * NN + t1 * 256 + ((l ^ i) << 2));
  }
  VW(8)  // aregA landed (8 newer = aregB still in flight)
#pragma unroll
  for (int i = 0; i < 8; ++i) {
    int row = 8 * w + i;
    *reinterpret_cast<f32x4*>(&smem[0][row][l << 2]) = aregA[i];
  }
  asm volatile("s_waitcnt lgkmcnt(0)" ::: "memory");
  SCHED0();
  __builtin_amdgcn_s_barrier();
  SCHED0();

  for (int it2 = 0; it2 < 6; ++it2) {
    ATTN_BODY(aregB, aregA, 2 * it2, 0)
    ATTN_BODY(aregA, aregB, 2 * it2 + 1, 1)
  }

  VW(0)
  __syncthreads();

  // ---- epilogue: cross-wave combine in LDS (pad-33 transpose -> d-major),
  // then coalesced atomicAdd partials into out/denom.
  float stot = sacc + __shfl_xor(sacc, 32);
  float* opart = &smem[0][0][0];          // [4][64][33]
  float* ssum = opart + 4 * 64 * 33;      // [4][32]
  if (l < 32) ssum[w * 32 + l31] = stot;
#pragma unroll
  for (int r = 0; r < 16; ++r) {
    int d = (r & 3) + 8 * (r >> 2) + 4 * lh;
    opart[w * 2112 + d * 33 + l31] = o0[r];
    opart[w * 2112 + (32 + d) * 33 + l31] = o1[r];
  }
  __syncthreads();

  if (tid < 32)
    atomicAdd(&denom[hh * NN + q0 + tid],
              ssum[tid] + ssum[32 + tid] + ssum[64 + tid] + ssum[96 + tid]);
#pragma unroll
  for (int k = 0; k < 8; ++k) {
    int idx = k * 256 + tid;
    int d = idx & 63, q = idx >> 6;  // consecutive tids -> consecutive d
    float ov = opart[d * 33 + q] + opart[2112 + d * 33 + q] +
               opart[4224 + d * 33 + q] + opart[6336 + d * 33 + q];
    atomicAdd(&out[(size_t)(hh * NN + q0 + q) * DOUT + d], ov);
  }
}

// ---------------- normalize: out /= denom, float4, exact coverage
// 1536 blocks x 256 threads x 4 floats = 1,572,864 = HEADS*NN*DOUT exactly.
__global__ __launch_bounds__(256) void norm_kernel(
    float* __restrict__ out, const float* __restrict__ denom) {
  int i = blockIdx.x * 256 + threadIdx.x;  // float4 index
  float dn = denom[i >> 4];                // same q for all 4 elements
  f32x4 v = reinterpret_cast<f32x4*>(out)[i];
  float inv = 1.0f / dn;
#pragma unroll
  for (int j = 0; j < 4; ++j) v[j] *= inv;
  reinterpret_cast<f32x4*>(out)[i] = v;
}

extern "C" void kernel_launch(void* const* d_in, const int* in_sizes, int n_in,
                              void* d_out, int out_size, void* d_ws, size_t ws_size,
                              hipStream_t stream) {
  const float* adj = (const float*)d_in[0];
  const float* h   = (const float*)d_in[1];
  const float* WQ  = (const float*)d_in[2];
  const float* bQ  = (const float*)d_in[3];
  const float* WK  = (const float*)d_in[4];
  const float* bK  = (const float*)d_in[5];
  const float* WV  = (const float*)d_in[6];
  const float* bV  = (const float*)d_in[7];
  float* out = (float*)d_out;

  if (ws_size < 10027008) return;  // ~9.6 MB scratch

  char* ws = (char*)d_ws;
  bf16_t* Wt    = (bf16_t*)ws;                 // [3][H][64][256] bf16      393,216 B
  bf16_t* Qb    = (bf16_t*)(ws + 393216);      // [H][N][64] bf16 (scaled)3,145,728 B
  bf16_t* Kf    = (bf16_t*)(ws + 3538944);     // [H] K fragments         3,145,728 B
  bf16_t* Vf    = (bf16_t*)(ws + 6684672);     // [H] V fragments         3,145,728 B
  float*  denom = (float*)(ws + 9830400);      // [H][N] f32                 98,304 B

  hipMemsetAsync(out, 0, (size_t)HEADS * NN * DOUT * sizeof(float), stream);
  hipMemsetAsync(denom, 0, (size_t)HEADS * NN * sizeof(float), stream);
  prepw_kernel<<<96, 256, 0, stream>>>(WQ, WK, WV, Wt);
  proj_kernel<<<dim3(96, 4), 256, 0, stream>>>(h, Wt, bQ, bK, bV, Qb, Kf, Vf);
  attn_kernel<<<1536, 256, 0, stream>>>(adj, Qb, Kf, Vf, out, denom);
  norm_kernel<<<1536, 256, 0, stream>>>(out, denom);
}